// Round 2
// baseline (151.522 us; speedup 1.0000x reference)
//
#include <hip/hip_runtime.h>
#include <math.h>

// SineSPE: qhat/khat = einsum('hdls,bhdsr,blhd->blhr', omega, zs, q|k)
// B=2 L=1024 H=8 D=64 S=10 R=128 -> 32 GEMMs of [1024 x 1280] x [1280 x 128]
// sharing per-(b,h) Z (bf16-ized in ws). A built on the fly in registers.

typedef short bf16x8 __attribute__((ext_vector_type(8)));
typedef float f32x16 __attribute__((ext_vector_type(16)));

__device__ __forceinline__ unsigned int rnd_bf16(float x) {
    union { float f; unsigned int u; } v; v.f = x;
    return v.u + 0x8000u;
}
// pack: cos -> low u16 (even k), sin -> high u16 (odd k)
__device__ __forceinline__ unsigned int pack_bf16(float c, float s) {
    return __builtin_amdgcn_perm(rnd_bf16(s), rnd_bf16(c), 0x07060302u);
}

// zt tile layout per (bh, kb): [r=0..127][kkl=0..63] bf16, contiguous 16KB.
// Also produces frof[h*640 + d*10 + s] = {sigmoid(f)/2 (rev/step), off/2pi}.
__global__ __launch_bounds__(256) void prep_z(
    const float* __restrict__ freqs, const float* __restrict__ offsets,
    const float* __restrict__ gains, const float* __restrict__ z,
    unsigned short* __restrict__ zt, float2* __restrict__ frof)
{
    const float scale = 0.011048543456039806f;  // 1/sqrt(R*D)
    int bid = blockIdx.x;           // 0..319
    int bh = bid / 20, kb = bid % 20;
    int h = bh & 7;
    int t = threadIdx.x;
    __shared__ unsigned short tr[128 * 65];

    if (t < 16) {                    // fold param prep in: 320*16 = 5120
        int i = bid * 16 + t;
        float f = freqs[i];
        float2 fo;
        fo.x = 0.5f / (1.0f + __expf(-f));
        fo.y = offsets[i] * 0.15915494309189535f;
        frof[i] = fo;
    }

    for (int i = 0; i < 32; i++) {
        int e = i * 256 + t;        // e = kkl*128 + r (coalesced on r)
        int kkl = e >> 7, r = e & 127;
        int kkg = kb * 64 + kkl;
        int d = kkg / 20, j = kkg - d * 20;
        int jm = (j < 10) ? j : j - 10;            // concat([g,g]) layout
        float gn = gains[(h * 64 + d) * 10 + jm];
        float g = fmaxf(gn, 0.0f) + log1pf(__expf(-fabsf(gn)));  // softplus
        float val = z[((size_t)bh * 1280 + kkg) * 128 + r] * g * scale;
        tr[r * 65 + kkl] = (unsigned short)(rnd_bf16(val) >> 16);
    }
    __syncthreads();
    size_t obase = (size_t)bid * 8192;
    for (int i = 0; i < 32; i++) {
        int e2 = i * 256 + t;       // e2 = r*64 + kkl (coalesced write)
        int r = e2 >> 6, kkl = e2 & 63;
        zt[obase + e2] = tr[r * 65 + kkl];
    }
}

__global__ __launch_bounds__(256, 1) void spe_gemm(
    const float* __restrict__ queries, const float* __restrict__ keys,
    const float2* __restrict__ frof, const unsigned short* __restrict__ zt,
    float* __restrict__ out)
{
    // Z: double-buffered, UNPADDED 128B rows with XOR-16B swizzle (conflict-free)
    __shared__ __align__(16) unsigned short Zsm[2][128 * 64];
    __shared__ __align__(16) float Qsm[128 * 68];   // f32, stride 68
    __shared__ __align__(16) float2 Fsm[640];       // {fr_rev, off_rev} for this h

    int bid = blockIdx.x;
    int bh = bid & 15;              // same-bh blocks share XCD (bid%8 pattern)
    int mtile = bid >> 4;           // 0..15 over stacked [q(8); k(8)]
    int b = bh >> 3, h = bh & 7;
    bool isQ = (mtile < 8);
    int l0 = (mtile & 7) * 128;

    int t = threadIdx.x;
    int lane = t & 63;
    int w = t >> 6;                 // wave owns rows [w*32, w*32+32) -> unique A work
    int hi = lane >> 5;             // k-half of A/B fragment
    int ml = lane & 31;
    int m = w * 32 + ml;            // row within 128-tile

    const float* src = isQ ? queries : keys;

    // ---- stage Q tile (f32) ----
    #pragma unroll
    for (int i = 0; i < 8; i++) {
        int e4 = i * 256 + t;
        int row = e4 >> 4, dq = (e4 & 15) * 4;
        float4 qv = *(const float4*)(src + (((size_t)(b * 1024 + l0 + row) * 8 + h) * 64 + dq));
        *(float4*)(Qsm + row * 68 + dq) = qv;
    }
    // ---- stage fr/off (zero the offset for K-side once, not per-pair) ----
    const float2* fsrc = frof + h * 640;
    float qmask = isQ ? 1.0f : 0.0f;
    for (int i = t; i < 640; i += 256) {
        float2 fo = fsrc[i];
        fo.y *= qmask;
        Fsm[i] = fo;
    }

    // ---- Z prologue: tile kb=0 -> buf0, tile kb=1 -> regs ----
    const uint4* ztb = (const uint4*)(zt + (size_t)bh * 20 * 8192);
    uint4 zr[4];
    #pragma unroll
    for (int i = 0; i < 4; i++) zr[i] = ztb[i * 256 + t];
    #pragma unroll
    for (int i = 0; i < 4; i++) {
        int e16 = i * 256 + t;
        int r = e16 >> 3, k8 = e16 & 7;
        *(uint4*)((char*)&Zsm[0][0] + r * 128 + ((k8 * 16) ^ ((r & 7) << 4))) = zr[i];
    }
    #pragma unroll
    for (int i = 0; i < 4; i++) zr[i] = ztb[1024 + i * 256 + t];

    f32x16 acc[4] = {};
    float lf = (float)(l0 + m);
    unsigned int swz = (unsigned int)(ml & 7) << 4;

    #pragma unroll 2
    for (int kb = 0; kb < 20; kb++) {
        __syncthreads();  // buf[kb&1] writes (prev iter) done; prev reads of buf[kb^1] done

        // ds_write next tile into buf[(kb+1)&1]
        #pragma unroll
        for (int i = 0; i < 4; i++) {
            int e16 = i * 256 + t;
            int r = e16 >> 3, k8 = e16 & 7;
            *(uint4*)((char*)&Zsm[(kb & 1) ^ 1][0] + r * 128 + ((k8 * 16) ^ ((r & 7) << 4))) = zr[i];
        }
        // prefetch tile kb+2 into regs (clamped; redundant at tail, never read)
        int nkb = (kb + 2 < 20) ? (kb + 2) : 19;
        #pragma unroll
        for (int i = 0; i < 4; i++) zr[i] = ztb[(size_t)nkb * 1024 + i * 256 + t];

        // ---- A fragments in registers: lane covers pairs pb..pb+3 per ks ----
        unsigned int afrag[4][4];
        int pb = kb * 32 + hi * 4;
        #pragma unroll
        for (int ks = 0; ks < 4; ks++) {
            #pragma unroll
            for (int j = 0; j < 4; j++) {
                int pp = pb + ks * 8 + j;          // pair index in [0,640)
                int d = (pp * 6554) >> 16;         // exact pp/10 for pp<1637
                float2 fo = Fsm[pp];
                float qv = Qsm[m * 68 + d];
                float ph = __builtin_amdgcn_fractf(fmaf(fo.x, lf, fo.y));  // revolutions
                float cv = __builtin_amdgcn_cosf(ph) * qv;   // v_cos: input in revs
                float sv = __builtin_amdgcn_sinf(ph) * qv;
                afrag[ks][j] = pack_bf16(cv, sv);
            }
        }

        // ---- MFMA: 4 ks-steps x 4 n-tiles ----
        const char* bufb = (const char*)&Zsm[kb & 1][0];
        #pragma unroll
        for (int ks = 0; ks < 4; ks++) {
            bf16x8 a = *(const bf16x8*)&afrag[ks][0];
            unsigned int koff = (unsigned int)(ks * 32 + hi * 16);
            #pragma unroll
            for (int nt = 0; nt < 4; nt++) {
                int n = nt * 32 + ml;
                bf16x8 bb = *(const bf16x8*)(bufb + n * 128 + (koff ^ swz));
                acc[nt] = __builtin_amdgcn_mfma_f32_32x32x16_bf16(a, bb, acc[nt], 0, 0, 0);
            }
        }
    }

    // ---- epilogue: C/D layout col=lane&31, row=(reg&3)+8*(reg>>2)+4*hi ----
    float* ob = out + (isQ ? (size_t)0 : (size_t)2 * 1024 * 8 * 128);
    size_t c0 = ((size_t)(b * 1024 + l0 + w * 32) * 8 + h) * 128;
    #pragma unroll
    for (int nt = 0; nt < 4; nt++) {
        int col = nt * 32 + ml;
        #pragma unroll
        for (int reg = 0; reg < 16; reg++) {
            int rowt = (reg & 3) + 8 * (reg >> 2) + 4 * hi;
            ob[c0 + (size_t)rowt * 1024 + col] = acc[nt][reg];
        }
    }
}

extern "C" void kernel_launch(void* const* d_in, const int* in_sizes, int n_in,
                              void* d_out, int out_size, void* d_ws, size_t ws_size,
                              hipStream_t stream) {
    const float* queries = (const float*)d_in[0];
    const float* keys    = (const float*)d_in[1];
    const float* freqs   = (const float*)d_in[2];
    const float* offsets = (const float*)d_in[3];
    const float* gains   = (const float*)d_in[4];
    const float* z       = (const float*)d_in[5];
    float* out = (float*)d_out;

    float2* frof = (float2*)d_ws;                              // 5120 float2 (40KB)
    unsigned short* zt = (unsigned short*)((char*)d_ws + 5120 * sizeof(float2));

    prep_z<<<320, 256, 0, stream>>>(freqs, offsets, gains, z, zt, frof);
    spe_gemm<<<256, 256, 0, stream>>>(queries, keys, frof, zt, out);
}